// Round 9
// baseline (43.462 us; speedup 1.0000x reference)
//
#include <hip/hip_runtime.h>
#include <hip/hip_fp16.h>

#define PP 7
#define SR 2
#define HH 128
#define WW 128
#define CC 256
#define PLANE (HH * WW)
#define CPW 8      // channels per wave
#define NCHUNK 8   // chunks per ROI (32 ch each); chunk id == XCD id

typedef const __attribute__((address_space(1))) void g_void;
typedef __attribute__((address_space(3))) void l_void;

// Async global->LDS, 16B per lane. LDS dest is wave-uniform base; HW scatters
// lane i to base + i*16. Global src is per-lane. Fire-and-forget vs vmcnt ->
// MLP independent of regalloc (the R5-R8 failure mode).
__device__ __forceinline__ void gload_lds16(const float* g, float* lds_base) {
  __builtin_amdgcn_global_load_lds((g_void*)g, (l_void*)lds_base, 16, 0, 0);
}

__global__ __launch_bounds__(256, 4) void roi_pool_kernel(
    const float* __restrict__ fm, const float* __restrict__ rois,
    float* __restrict__ out, int N) {
  const int nwg = gridDim.x;          // N * NCHUNK
  const int bid = blockIdx.x;
  // chunk == XCD (bid&7): XCD x streams channels [32x,32x+32) over ROIs in
  // order; ROIs sorted by image -> instantaneous L2 set ~= 32ch x 1 img = 2MB
  int roi, chunk;
  if ((nwg & 7) == 0) { chunk = bid & 7; roi = bid >> 3; }
  else               { chunk = bid & 7; roi = bid >> 3; }
  const int t = threadIdx.x;
  const int wave = t >> 6;
  const int lane = t & 63;

  __shared__ float4 stage[4][CPW][64];   // 32 KB, wave-private slices
  __shared__ float WX[WW], WY[HH];
  __shared__ int rowIdx[32];
  __shared__ float rowW[32];

  if (t < 128) { WX[t] = 0.f; WY[t] = 0.f; }
  __syncthreads();

  // ---- geometry (redundant per-thread) ----
  const float bf = rois[roi * 6 + 0];
  const float cx = rois[roi * 6 + 2];
  const float cy = rois[roi * 6 + 3];
  const float w_ = rois[roi * 6 + 4];
  const float h_ = rois[roi * 6 + 5];

  // f16 round-trip, contraction-free (match jnp float16 cast semantics)
  const float x1 = __half2float(__float2half(
      __fmul_rn(__fsub_rn(cx, __fmul_rn(0.5f, w_)), 128.0f)));
  const float y1 = __half2float(__float2half(
      __fmul_rn(__fsub_rn(cy, __fmul_rn(0.5f, h_)), 128.0f)));
  const float x2 = __half2float(__float2half(
      __fmul_rn(__fadd_rn(cx, __fmul_rn(0.5f, w_)), 128.0f)));
  const float y2 = __half2float(__float2half(
      __fmul_rn(__fadd_rn(cy, __fmul_rn(0.5f, h_)), 128.0f)));

  const float sx = fmaxf(__fsub_rn(x2, x1), 1.0f) / 7.0f;
  const float sy = fmaxf(__fsub_rn(y2, y1), 1.0f) / 7.0f;

  // ---- scatter per-axis sample weights (threads 0..27, all in wave 0) ----
  if (t < 2 * PP * SR) {
    const int isX = t >= PP * SR;
    const int i = t - isX * PP * SR;             // 0..13
    const float off = (float)(i >> 1) + ((float)(i & 1) + 0.5f) * 0.5f;
    const float pos = __fadd_rn(isX ? x1 : y1, __fmul_rn(off, isX ? sx : sy));
    if (pos > -1.0f && pos < 128.0f) {
      const float pc = fminf(fmaxf(pos, 0.0f), 127.0f);
      const int p0 = (int)floorf(pc);
      const int p1 = min(p0 + 1, 127);
      const float l = pc - (float)p0;
      float* Warr = isX ? WX : WY;
      atomicAdd(&Warr[p0], 1.0f - l);
      atomicAdd(&Warr[p1], l);
    }
  }
  __syncthreads();

  // ---- per-wave ballot compaction (identical results in every wave) ----
  const float wy0 = WY[lane], wy1 = WY[lane + 64];
  const unsigned long long by0 = __ballot(wy0 != 0.f);
  const unsigned long long by1 = __ballot(wy1 != 0.f);
  const unsigned long long below = (lane == 0) ? 0ull : (~0ull >> (64 - lane));
  const int n0 = __popcll(by0);
  if (wave == 0) {
    if (wy0 != 0.f) { const int p = __popcll(by0 & below); rowIdx[p] = lane; rowW[p] = wy0; }
    if (wy1 != 0.f) { const int p = n0 + __popcll(by1 & below); rowIdx[p] = lane + 64; rowW[p] = wy1; }
  }
  const int nrows = n0 + __popcll(by1);

  const float wxa = WX[lane], wxb = WX[lane + 64];
  const unsigned long long bx0 = __ballot(wxa != 0.f);
  const unsigned long long bx1 = __ballot(wxb != 0.f);
  const int xlo = bx0 ? __builtin_ctzll(bx0) : (bx1 ? 64 + __builtin_ctzll(bx1) : 0);
  const int xhi = bx1 ? 64 + (63 - __builtin_clzll(bx1))
                      : (bx0 ? (63 - __builtin_clzll(bx0)) : -1);
  __syncthreads();

  // ---- main gather: (rowstep rows) x (nx4 float4 cols) lane layout ----
  float acc[CPW];
  #pragma unroll
  for (int c = 0; c < CPW; ++c) acc[c] = 0.f;

  const int c0 = chunk * (NCHUNK * 4) + wave * CPW;   // chunk*32 + wave*8

  if (nrows > 0 && xhi >= 0) {          // wave-uniform branch
    const int b = (int)bf;
    const int x4lo = xlo >> 2;
    const int x4cnt = (xhi >> 2) - x4lo + 1;                    // <= 15
    const int l2 = (x4cnt <= 1) ? 0 : (32 - __clz(x4cnt - 1));  // ceil log2
    const int nx4 = 1 << l2;
    const int rowstep = 64 >> l2;
    const int xi = lane & (nx4 - 1);
    const int ri = lane >> l2;
    const bool xv = xi < x4cnt;
    const int col4 = xv ? (x4lo + xi) : x4lo;                   // dup lanes share line
    float4 wx4 = make_float4(0.f, 0.f, 0.f, 0.f);
    if (xv) wx4 = *(const float4*)&WX[col4 << 2];
    const float* cb = fm + ((size_t)b * CC + c0) * PLANE + (col4 << 2);

    for (int r0 = 0; r0 < nrows; r0 += rowstep) {
      const int rI = r0 + ri;
      const bool rv = rI < nrows;
      const int row = rowIdx[rv ? rI : 0];
      const float wy = rv ? rowW[rI] : 0.f;
      const float w0 = wx4.x * wy, w1 = wx4.y * wy;
      const float w2 = wx4.z * wy, w3 = wx4.w * wy;
      const float* p = cb + row * WW;

      // 8 async direct-to-LDS loads in flight, one vmcnt exposure per iter
      #pragma unroll
      for (int c = 0; c < CPW; ++c)
        gload_lds16(p + c * PLANE, (float*)&stage[wave][c][0]);
      asm volatile("s_waitcnt vmcnt(0)" ::: "memory");
      __builtin_amdgcn_sched_barrier(0);
      #pragma unroll
      for (int c = 0; c < CPW; ++c) {
        const float4 v = stage[wave][c][lane];
        acc[c] = fmaf(w0, v.x, acc[c]);
        acc[c] = fmaf(w1, v.y, acc[c]);
        acc[c] = fmaf(w2, v.z, acc[c]);
        acc[c] = fmaf(w3, v.w, acc[c]);
      }
    }
  }

  // ---- 64-lane reduce per channel, lane c writes channel c ----
  const size_t obase = (size_t)roi * CC + c0;
  #pragma unroll
  for (int c = 0; c < CPW; ++c) {
    float v = acc[c];
    #pragma unroll
    for (int m = 32; m >= 1; m >>= 1) v += __shfl_xor(v, m, 64);
    if (lane == c) out[obase + c] = v * (1.0f / 196.0f);
  }

  // ---- gt output ----
  if (chunk == 0 && t == 0) out[(size_t)N * CC + roi] = rois[roi * 6 + 1];
}

extern "C" void kernel_launch(void* const* d_in, const int* in_sizes, int n_in,
                              void* d_out, int out_size, void* d_ws, size_t ws_size,
                              hipStream_t stream) {
  const float* fm   = (const float*)d_in[0];
  const float* rois = (const float*)d_in[1];
  float* out = (float*)d_out;
  const int N = in_sizes[1] / 6;
  roi_pool_kernel<<<N * NCHUNK, 256, 0, stream>>>(fm, rois, out, N);
}